// Round 20
// baseline (207.388 us; speedup 1.0000x reference)
//
#include <hip/hip_runtime.h>
#include <hip/hip_bf16.h>

// GRNNTransformGated, round 19: widen the fused chain (2 blocks/CU).
// Post-mortem ledger (keep — hard-won):
//  R4: agent-scope spin grid barriers ~137us -> never.
//  R12: (256,3) spilled mm3's az[4][4] (VGPR 84, WRITE 96-340MB). (256,2)
//      clean. RULE: VGPR below live-acc arithmetic == spill.
//  R13/R14: fusing big levels at low occupancy loses; occupancy wins.
//  R15: +8KB LDS cost a block/CU on big levels; fused (256,1) gained from
//      separate s_hH.
//  R16: per-lane direct c loads on MFMA dep chain in glob tile -> regression.
//  R17/R18: 198us plateau; bare launch-bounds neutral. Big levels at their
//      tile-design latency floor (pipes <35%, session variance +-10%).
//  R19 (this): fused chain was B=256 = 1 block/CU while 57KB LDS permits 2.
//      fused_mid -> B=512, j=8..3 (nested slices need R_j >= B, holds to
//      j=3); fused_tail -> B=64, j=2..0. Expect 2-block TLP to hide the
//      per-phase latency of the serial chain.
// Carried: in-place up regions in u_all; exp2-folded W_r/b_r/W_z/b_z;
// operand-swapped MFMA (lane gets 4 consecutive out-cols of one row);
// coalesced up-store via LDS round-trip; MFMA-u; j=11 computes level-12
// children u from contents (u12 never materialized).

#define LOG2E 1.4426950408889634f
#define OSTR 76   // out-staging row stride (elements)

typedef __bf16 bf16x8 __attribute__((ext_vector_type(8)));
typedef unsigned short u16x8 __attribute__((ext_vector_type(8)));
typedef float f32x4 __attribute__((ext_vector_type(4)));
typedef unsigned short bfr;   // raw bf16 bits

__device__ __forceinline__ float bfr2f(bfr v) { return __uint_as_float(((unsigned)v) << 16); }
__device__ __forceinline__ bfr f2bfr(float f) {
    __hip_bfloat16 h = __float2bfloat16(f);
    return __builtin_bit_cast(bfr, h);
}
__device__ __forceinline__ float fexp2(float x) {
#if __has_builtin(__builtin_amdgcn_exp2f)
    return __builtin_amdgcn_exp2f(x);
#else
    return exp2f(x);
#endif
}
__device__ __forceinline__ float frcp(float x) {
#if __has_builtin(__builtin_amdgcn_rcpf)
    return __builtin_amdgcn_rcpf(x);
#else
    return 1.f / x;
#endif
}

// fragment-order address (elements): frag (Mt,kt), lane (ln,q), 8 elems
__device__ __forceinline__ int fidx(int Mt, int kt, int q, int ln, int KT) {
    return ((((Mt * KT + kt) * 4 + q) * 16 + ln) * 8);
}

// level-j up region start (elements) within u_all
__device__ __host__ __forceinline__ size_t lvloff(int j) {
    return (size_t)((64 << j) - 64) * 64;
}

__device__ __forceinline__ void pack_one(const float* __restrict__ W, bfr* __restrict__ dst,
                                         int d, int K, float scale) {
    int KT = K >> 5;
    int j = d & 7, lnc = (d >> 3) & 15, q = (d >> 7) & 3;
    int t1 = d >> 9;
    int kt = t1 % KT, ntile = t1 / KT;
    int ncol = ntile * 16 + lnc;
    int k = kt * 32 + q * 8 + j;
    dst[d] = f2bfr(W[(size_t)ncol * K + k] * scale);
}

__global__ void convert_weights(const float* __restrict__ Wr, const float* __restrict__ Wh,
                                const float* __restrict__ Wz, const float* __restrict__ Wu,
                                const float* __restrict__ br, const float* __restrict__ bz,
                                bfr* __restrict__ wr, bfr* __restrict__ wh, bfr* __restrict__ wz,
                                bfr* __restrict__ wu,
                                float* __restrict__ brs, float* __restrict__ bzs) {
    int i = blockIdx.x * 256 + threadIdx.x;   // grid covers 65536
    if (i < 36864) pack_one(Wr, wr, i, 192, LOG2E);
    if (i < 12288) pack_one(Wh, wh, i, 192, 1.f);
    if (i < 65536) pack_one(Wz, wz, i, 256, LOG2E);
    if (i < 2048) {   // W_u (64x7) -> frag order K=32, zero-padded
        int j = i & 7, lnc = (i >> 3) & 15, q = (i >> 7) & 3, ntile = i >> 9;
        int k = q * 8 + j, ncol = ntile * 16 + lnc;
        wu[i] = (k < 7) ? f2bfr(Wu[ncol * 7 + k]) : (bfr)0;
    }
    if (i < 192) brs[i] = br[i] * LOG2E;
    if (i < 256) bzs[i] = bz[i] * LOG2E;
}

// Stage `rows` contents rows (7 f32 each) as bf16 B-frags (K=32 padded).
__device__ __forceinline__ void stage_c(const float* __restrict__ csrc, int rows,
                                        bfr* s_c) {
    const int tid = threadIdx.x;
    for (int t = tid; t < rows * 4; t += 256) {
        int row = t >> 2, qg = t & 3;
        ushort v[8] = {0, 0, 0, 0, 0, 0, 0, 0};
        if (qg == 0) {
            const float* cp = csrc + (size_t)row * 7;
#pragma unroll
            for (int k = 0; k < 7; ++k) v[k] = f2bfr(cp[k]);
        }
        *(uint4*)&s_c[(((row >> 4) * 4 + qg) * 16 + (row & 15)) * 8] = *(const uint4*)v;
    }
}

// Build a contents B-fragment directly from global (q==0 lanes hold k=0..6).
// Used ONLY in the (256,1) fused tiles (R16: hurts the glob tile).
__device__ __forceinline__ bf16x8 load_c_frag(const float* __restrict__ c,
                                              size_t grow, bool active) {
    u16x8 cv = {0, 0, 0, 0, 0, 0, 0, 0};
    if (active) {
        const float* cp = c + grow * 7;
#pragma unroll
        for (int k = 0; k < 7; ++k) cv[k] = f2bfr(cp[k]);
    }
    return __builtin_bit_cast(bf16x8, cv);
}

// Coalesced up-store epilogue via LDS round-trip (R12 form, internal syncs).
__device__ __forceinline__ void store_up_coalesced(
    int row0, int rows, bfr* __restrict__ u_io,
    const ushort (&ovv)[4][4], int Mtn, bfr* s_t)
{
    const int tid = threadIdx.x;
    const int lane = tid & 63, w = tid >> 6;
    const int ln = lane & 15, q = lane >> 4;
    const int colbase = w * 16 + q * 4;
    __syncthreads();
#pragma unroll
    for (int Mt = 0; Mt < 4; ++Mt) {
        if (Mt < Mtn) {
            int row = Mt * 16 + ln;
            if (row < rows)
                *(uint2*)&s_t[row * OSTR + colbase] = *(const uint2*)ovv[Mt];
        }
    }
    __syncthreads();
#pragma unroll
    for (int it = 0; it < 2; ++it) {
        int idx = it * 256 + tid;
        int row = idx >> 3, ck = idx & 7;
        if (row < rows)
            *(uint4*)&u_io[(size_t)(row0 + row) * 64 + ck * 8] =
                *(const uint4*)&s_t[row * OSTR + ck * 8];
    }
}

// mm_u: u = relu(c @ W_u^T) via MFMA from staged c frags into s_hhu (kt4..5).
__device__ __forceinline__ void mmu_own(const bfr* s_c, bfr* s_hhu, bf16x8 awu,
                                        f32x4 bu4, int Mtn, int ln, int q,
                                        int colbase) {
#pragma unroll
    for (int Mt = 0; Mt < 4; ++Mt) {
        if (Mt < Mtn) {
            bf16x8 Bc = *(const bf16x8*)&s_c[((Mt * 4 + q) * 16 + ln) * 8];
            f32x4 acc = {0.f, 0.f, 0.f, 0.f};
            acc = __builtin_amdgcn_mfma_f32_16x16x32_bf16(awu, Bc, acc, 0, 0, 0);
            int kk = 128 + colbase;
            int addr = fidx(Mt, kk >> 5, (kk >> 3) & 3, ln, 6) + (kk & 7);
            ushort uv[4];
#pragma unroll
            for (int r = 0; r < 4; ++r) uv[r] = f2bfr(fmaxf(acc[r] + bu4[r], 0.f));
            *(uint2*)&s_hhu[addr] = *(const uint2*)uv;
        }
    }
}

// ============ glob tile (R12/R17): per-phase L2 weight loads, 48KB =========
template <bool CHILD_U>
__device__ __forceinline__ void tile_glob(
    int row0,
    const bfr* __restrict__ ch, const float* __restrict__ c_child,
    const float* __restrict__ c_own, bfr* __restrict__ u_io,
    const bfr* __restrict__ wu, const float* __restrict__ b_u,
    const bfr* __restrict__ wr, const float* __restrict__ brs,
    const bfr* __restrict__ wh, const float* __restrict__ b_h,
    const bfr* __restrict__ wz, const float* __restrict__ bzs,
    bfr* s_hhu, bfr* s_t)
{
    bfr* s_hH = s_t;   // alias: h_H written only after all t reads done
    const int tid = threadIdx.x;
    const int lane = tid & 63, w = tid >> 6;
    const int ln = lane & 15, q = lane >> 4;
    const int colbase = w * 16 + q * 4;

    // ---- stage children + own contents (cooperative) ----
    if (!CHILD_U) {
#pragma unroll
        for (int it = 0; it < 4; ++it) {
            int idx = it * 256 + tid;
            int lns = idx & 15, qs = (idx >> 4) & 3, kts = (idx >> 6) & 3, Mts = idx >> 8;
            int row = Mts * 16 + lns;
            int k = kts * 32 + qs * 8;
            const bfr* src = (k < 64)
                ? ch + (size_t)(2 * (row0 + row)) * 64 + k
                : ch + (size_t)(2 * (row0 + row) + 1) * 64 + (k - 64);
            *(uint4*)&s_hhu[fidx(Mts, kts, qs, lns, 6)] = *(const uint4*)src;
        }
    } else {
        stage_c(c_child + (size_t)(2 * row0) * 7, 128, s_t + 2048);
    }
    stage_c(c_own + (size_t)row0 * 7, 64, s_t);
    __syncthreads();

    // ---- mm_u ----
    {
        bf16x8 awu = *(const bf16x8*)&wu[fidx(w, 0, q, ln, 1)];
        f32x4 bu4 = *(const f32x4*)&b_u[colbase];
        if (CHILD_U) {
#pragma unroll
            for (int Mt = 0; Mt < 8; ++Mt) {
                bf16x8 Bc = *(const bf16x8*)&s_t[2048 + (((Mt * 4 + q) * 16 + ln) * 8)];
                f32x4 acc = {0.f, 0.f, 0.f, 0.f};
                acc = __builtin_amdgcn_mfma_f32_16x16x32_bf16(awu, Bc, acc, 0, 0, 0);
                int crow = Mt * 16 + ln;
                int row = crow >> 1;
                int kk = (crow & 1) * 64 + colbase;
                int addr = fidx(row >> 4, kk >> 5, (kk >> 3) & 3, row & 15, 6) + (kk & 7);
                ushort uv[4];
#pragma unroll
                for (int r = 0; r < 4; ++r) uv[r] = f2bfr(fmaxf(acc[r] + bu4[r], 0.f));
                *(uint2*)&s_hhu[addr] = *(const uint2*)uv;
            }
        }
        mmu_own(s_t, s_hhu, awu, bu4, 4, ln, q, colbase);
    }
    __syncthreads();

    // ---- mm1 ----
    {
        bf16x8 Af[3][6];
#pragma unroll
        for (int nt = 0; nt < 3; ++nt)
#pragma unroll
            for (int kt = 0; kt < 6; ++kt)
                Af[nt][kt] = *(const bf16x8*)&wr[fidx(w * 3 + nt, kt, q, ln, 6)];
#pragma unroll
        for (int Mt = 0; Mt < 4; ++Mt) {
            bf16x8 Bf[6];
#pragma unroll
            for (int kt = 0; kt < 6; ++kt)
                Bf[kt] = *(const bf16x8*)&s_hhu[fidx(Mt, kt, q, ln, 6)];
#pragma unroll
            for (int nt = 0; nt < 3; ++nt) {
                int cb1 = (w * 3 + nt) * 16 + q * 4;
                f32x4 acc = {0.f, 0.f, 0.f, 0.f};
#pragma unroll
                for (int kt = 0; kt < 6; ++kt)
                    acc = __builtin_amdgcn_mfma_f32_16x16x32_bf16(Af[nt][kt], Bf[kt], acc, 0, 0, 0);
                f32x4 br4 = *(const f32x4*)&brs[cb1];
                int addr = fidx(Mt, cb1 >> 5, (cb1 >> 3) & 3, ln, 6) + (cb1 & 7);
                ushort hh[4], tt[4];
                *(uint2*)hh = *(const uint2*)&s_hhu[addr];
#pragma unroll
                for (int r = 0; r < 4; ++r) {
                    float e = fexp2(-(acc[r] + br4[r]));
                    tt[r] = f2bfr(frcp(1.f + e) * bfr2f(hh[r]));
                }
                *(uint2*)&s_t[addr] = *(const uint2*)tt;
            }
        }
    }
    __syncthreads();

    // ---- mm2: acc in regs; after all t reads, write aliased s_hH ----
    f32x4 hacc[4];
    {
        bf16x8 Ah[6];
#pragma unroll
        for (int kt = 0; kt < 6; ++kt)
            Ah[kt] = *(const bf16x8*)&wh[fidx(w, kt, q, ln, 6)];
#pragma unroll
        for (int Mt = 0; Mt < 4; ++Mt) {
            f32x4 acc = {0.f, 0.f, 0.f, 0.f};
#pragma unroll
            for (int kt = 0; kt < 6; ++kt) {
                bf16x8 Bf = *(const bf16x8*)&s_t[fidx(Mt, kt, q, ln, 6)];
                acc = __builtin_amdgcn_mfma_f32_16x16x32_bf16(Ah[kt], Bf, acc, 0, 0, 0);
            }
            hacc[Mt] = acc;
        }
    }
    __syncthreads();
    {
        f32x4 bh4 = *(const f32x4*)&b_h[colbase];
#pragma unroll
        for (int Mt = 0; Mt < 4; ++Mt) {
            int addr = fidx(Mt, colbase >> 5, (colbase >> 3) & 3, ln, 2) + (colbase & 7);
            ushort hv[4];
#pragma unroll
            for (int r = 0; r < 4; ++r) hv[r] = f2bfr(fmaxf(hacc[Mt][r] + bh4[r], 0.f));
            *(uint2*)&s_hH[addr] = *(const uint2*)hv;
        }
    }
    __syncthreads();

    // ---- mm3 (g-outer, az[4][4] resident) + gate ----
    {
        f32x4 az[4][4];
#pragma unroll
        for (int Mt = 0; Mt < 4; ++Mt)
#pragma unroll
            for (int g = 0; g < 4; ++g) az[Mt][g] = (f32x4){0.f, 0.f, 0.f, 0.f};
#pragma unroll
        for (int g = 0; g < 4; ++g) {
            bf16x8 Aw[8];
#pragma unroll
            for (int kt = 0; kt < 8; ++kt)
                Aw[kt] = *(const bf16x8*)&wz[fidx(g * 4 + w, kt, q, ln, 8)];
#pragma unroll
            for (int Mt = 0; Mt < 4; ++Mt) {
                f32x4 acc = az[Mt][g];
                acc = __builtin_amdgcn_mfma_f32_16x16x32_bf16(
                    Aw[0], *(const bf16x8*)&s_hH[fidx(Mt, 0, q, ln, 2)], acc, 0, 0, 0);
                acc = __builtin_amdgcn_mfma_f32_16x16x32_bf16(
                    Aw[1], *(const bf16x8*)&s_hH[fidx(Mt, 1, q, ln, 2)], acc, 0, 0, 0);
#pragma unroll
                for (int kt = 0; kt < 6; ++kt)
                    acc = __builtin_amdgcn_mfma_f32_16x16x32_bf16(
                        Aw[2 + kt], *(const bf16x8*)&s_hhu[fidx(Mt, kt, q, ln, 6)], acc, 0, 0, 0);
                az[Mt][g] = acc;
            }
        }
        f32x4 bz0 = *(const f32x4*)&bzs[colbase];
        f32x4 bz1 = *(const f32x4*)&bzs[64 + colbase];
        f32x4 bz2 = *(const f32x4*)&bzs[128 + colbase];
        f32x4 bz3 = *(const f32x4*)&bzs[192 + colbase];
        ushort ovv[4][4];
#pragma unroll
        for (int Mt = 0; Mt < 4; ++Mt) {
            int aH = fidx(Mt, colbase >> 5, (colbase >> 3) & 3, ln, 2) + (colbase & 7);
            int a0 = fidx(Mt, colbase >> 5, (colbase >> 3) & 3, ln, 6) + (colbase & 7);
            int c1 = 64 + colbase, c2 = 128 + colbase;
            int a1 = fidx(Mt, c1 >> 5, (c1 >> 3) & 3, ln, 6) + (c1 & 7);
            int a2 = fidx(Mt, c2 >> 5, (c2 >> 3) & 3, ln, 6) + (c2 & 7);
            ushort hHv[4], u0[4], u1[4], u2[4];
            *(uint2*)hHv = *(const uint2*)&s_hH[aH];
            *(uint2*)u0 = *(const uint2*)&s_hhu[a0];
            *(uint2*)u1 = *(const uint2*)&s_hhu[a1];
            *(uint2*)u2 = *(const uint2*)&s_hhu[a2];
#pragma unroll
            for (int r = 0; r < 4; ++r) {
                float e0 = fexp2(az[Mt][0][r] + bz0[r]);
                float e1 = fexp2(az[Mt][1][r] + bz1[r]);
                float e2 = fexp2(az[Mt][2][r] + bz2[r]);
                float e3 = fexp2(az[Mt][3][r] + bz3[r]);
                float inv = frcp(e0 + e1 + e2 + e3);
                float v = (e0 * bfr2f(hHv[r]) + e1 * bfr2f(u0[r]) +
                           e2 * bfr2f(u1[r]) + e3 * bfr2f(u2[r])) * inv;
                ovv[Mt][r] = f2bfr(v);
            }
        }
        store_up_coalesced(row0, 64, u_io, ovv, 4, s_t);
    }
}

__global__ __launch_bounds__(256, 2) void level11_kernel(
    const float* __restrict__ c12, const float* __restrict__ c11,
    bfr* __restrict__ u_io,
    const bfr* __restrict__ wr, const float* __restrict__ brs,
    const bfr* __restrict__ wh, const float* __restrict__ b_h,
    const bfr* __restrict__ wz, const float* __restrict__ bzs,
    const bfr* __restrict__ wu, const float* __restrict__ b_u)
{
    __shared__ bfr s_hhu[12288];
    __shared__ bfr s_t[12288];
    tile_glob<true>(blockIdx.x * 64, nullptr, c12, c11, u_io,
                    wu, b_u, wr, brs, wh, b_h, wz, bzs, s_hhu, s_t);
}

__global__ __launch_bounds__(256, 2) void level_kernel(
    const bfr* __restrict__ ch, const float* __restrict__ c_own,
    bfr* __restrict__ u_io,
    const bfr* __restrict__ wr, const float* __restrict__ brs,
    const bfr* __restrict__ wh, const float* __restrict__ b_h,
    const bfr* __restrict__ wz, const float* __restrict__ bzs,
    const bfr* __restrict__ wu, const float* __restrict__ b_u)
{
    __shared__ bfr s_hhu[12288];
    __shared__ bfr s_t[12288];
    tile_glob<false>(blockIdx.x * 64, ch, nullptr, c_own, u_io,
                     wu, b_u, wr, brs, wh, b_h, wz, bzs, s_hhu, s_t);
}

// ========= fused (256,1) variant: register-persistent weights (R15) ========
__device__ __forceinline__ void load_wregs(
    const bfr* __restrict__ wr, const bfr* __restrict__ wh, const bfr* __restrict__ wz,
    const bfr* __restrict__ wu, int w, int q, int ln,
    bf16x8 (&Af)[3][6], bf16x8 (&Ah)[6], bf16x8 (&Aw)[4][8], bf16x8& awu)
{
#pragma unroll
    for (int nt = 0; nt < 3; ++nt)
#pragma unroll
        for (int kt = 0; kt < 6; ++kt)
            Af[nt][kt] = *(const bf16x8*)&wr[fidx(w * 3 + nt, kt, q, ln, 6)];
#pragma unroll
    for (int kt = 0; kt < 6; ++kt)
        Ah[kt] = *(const bf16x8*)&wh[fidx(w, kt, q, ln, 6)];
#pragma unroll
    for (int g = 0; g < 4; ++g)
#pragma unroll
        for (int kt = 0; kt < 8; ++kt)
            Aw[g][kt] = *(const bf16x8*)&wz[fidx(g * 4 + w, kt, q, ln, 8)];
    awu = *(const bf16x8*)&wu[fidx(w, 0, q, ln, 1)];
}

__device__ __forceinline__ void tile_regs(
    int row0, int rows,
    const bfr* __restrict__ ch, const float* __restrict__ c_own,
    bfr* __restrict__ u_io,
    const bf16x8 awu, const float* __restrict__ b_u,
    const bf16x8 (&Af)[3][6], const bf16x8 (&Ah)[6], const bf16x8 (&Aw)[4][8],
    const float* __restrict__ brs, const float* __restrict__ b_h,
    const float* __restrict__ bzs,
    float* __restrict__ outp, bfr* s_hhu, bfr* s_t, bfr* s_hH)
{
    const int tid = threadIdx.x;
    const int lane = tid & 63, w = tid >> 6;
    const int ln = lane & 15, q = lane >> 4;
    const int Mtn = (rows + 15) >> 4;
    const int colbase = w * 16 + q * 4;

    __syncthreads();   // chain: prior coop-store reads + global visibility

    // ---- phase A ----
#pragma unroll
    for (int it = 0; it < 4; ++it) {
        int idx = it * 256 + tid;
        int lns = idx & 15, qs = (idx >> 4) & 3, kts = (idx >> 6) & 3, Mts = idx >> 8;
        int row = Mts * 16 + lns;
        if (row < rows) {
            int k = kts * 32 + qs * 8;
            const bfr* src = (k < 64)
                ? ch + (size_t)(2 * (row0 + row)) * 64 + k
                : ch + (size_t)(2 * (row0 + row) + 1) * 64 + (k - 64);
            *(uint4*)&s_hhu[fidx(Mts, kts, qs, lns, 6)] = *(const uint4*)src;
        }
    }
    {
        f32x4 bu4 = *(const f32x4*)&b_u[colbase];
#pragma unroll
        for (int Mt = 0; Mt < 4; ++Mt) {
            if (Mt < Mtn) {
                int row = Mt * 16 + ln;
                bf16x8 Bc = load_c_frag(c_own, (size_t)row0 + row, q == 0 && row < rows);
                f32x4 acc = {0.f, 0.f, 0.f, 0.f};
                acc = __builtin_amdgcn_mfma_f32_16x16x32_bf16(awu, Bc, acc, 0, 0, 0);
                int kk = 128 + colbase;
                int addr = fidx(Mt, kk >> 5, (kk >> 3) & 3, ln, 6) + (kk & 7);
                ushort uv[4];
#pragma unroll
                for (int r = 0; r < 4; ++r) uv[r] = f2bfr(fmaxf(acc[r] + bu4[r], 0.f));
                *(uint2*)&s_hhu[addr] = *(const uint2*)uv;
            }
        }
    }
    __syncthreads();

    // ---- mm1 ----
#pragma unroll
    for (int Mt = 0; Mt < 4; ++Mt) {
        if (Mt < Mtn) {
            bf16x8 Bf[6];
#pragma unroll
            for (int kt = 0; kt < 6; ++kt)
                Bf[kt] = *(const bf16x8*)&s_hhu[fidx(Mt, kt, q, ln, 6)];
#pragma unroll
            for (int nt = 0; nt < 3; ++nt) {
                int cb1 = (w * 3 + nt) * 16 + q * 4;
                f32x4 acc = {0.f, 0.f, 0.f, 0.f};
#pragma unroll
                for (int kt = 0; kt < 6; ++kt)
                    acc = __builtin_amdgcn_mfma_f32_16x16x32_bf16(Af[nt][kt], Bf[kt], acc, 0, 0, 0);
                f32x4 br4 = *(const f32x4*)&brs[cb1];
                int addr = fidx(Mt, cb1 >> 5, (cb1 >> 3) & 3, ln, 6) + (cb1 & 7);
                ushort hh[4], tt[4];
                *(uint2*)hh = *(const uint2*)&s_hhu[addr];
#pragma unroll
                for (int r = 0; r < 4; ++r) {
                    float e = fexp2(-(acc[r] + br4[r]));
                    tt[r] = f2bfr(frcp(1.f + e) * bfr2f(hh[r]));
                }
                *(uint2*)&s_t[addr] = *(const uint2*)tt;
            }
        }
    }
    __syncthreads();

    // ---- mm2 -> s_hH direct (separate region) ----
    {
        f32x4 bh4 = *(const f32x4*)&b_h[colbase];
#pragma unroll
        for (int Mt = 0; Mt < 4; ++Mt) {
            if (Mt < Mtn) {
                f32x4 acc = {0.f, 0.f, 0.f, 0.f};
#pragma unroll
                for (int kt = 0; kt < 6; ++kt) {
                    bf16x8 Bf = *(const bf16x8*)&s_t[fidx(Mt, kt, q, ln, 6)];
                    acc = __builtin_amdgcn_mfma_f32_16x16x32_bf16(Ah[kt], Bf, acc, 0, 0, 0);
                }
                int addr = fidx(Mt, colbase >> 5, (colbase >> 3) & 3, ln, 2) + (colbase & 7);
                ushort hv[4];
#pragma unroll
                for (int r = 0; r < 4; ++r) hv[r] = f2bfr(fmaxf(acc[r] + bh4[r], 0.f));
                *(uint2*)&s_hH[addr] = *(const uint2*)hv;
            }
        }
    }
    __syncthreads();

    // ---- mm3 per-Mt + gate -> stage rows in s_t ----
    {
        f32x4 bz0 = *(const f32x4*)&bzs[colbase];
        f32x4 bz1 = *(const f32x4*)&bzs[64 + colbase];
        f32x4 bz2 = *(const f32x4*)&bzs[128 + colbase];
        f32x4 bz3 = *(const f32x4*)&bzs[192 + colbase];
#pragma unroll
        for (int Mt = 0; Mt < 4; ++Mt) {
            if (Mt < Mtn) {
                bf16x8 Az[8];
                Az[0] = *(const bf16x8*)&s_hH[fidx(Mt, 0, q, ln, 2)];
                Az[1] = *(const bf16x8*)&s_hH[fidx(Mt, 1, q, ln, 2)];
#pragma unroll
                for (int kt = 0; kt < 6; ++kt)
                    Az[2 + kt] = *(const bf16x8*)&s_hhu[fidx(Mt, kt, q, ln, 6)];
                f32x4 azg[4];
#pragma unroll
                for (int g = 0; g < 4; ++g) {
                    f32x4 acc = {0.f, 0.f, 0.f, 0.f};
#pragma unroll
                    for (int kt = 0; kt < 8; ++kt)
                        acc = __builtin_amdgcn_mfma_f32_16x16x32_bf16(Aw[g][kt], Az[kt], acc, 0, 0, 0);
                    azg[g] = acc;
                }
                int row = Mt * 16 + ln;
                if (row < rows) {
                    int aH = fidx(Mt, colbase >> 5, (colbase >> 3) & 3, ln, 2) + (colbase & 7);
                    int a0 = fidx(Mt, colbase >> 5, (colbase >> 3) & 3, ln, 6) + (colbase & 7);
                    int c1 = 64 + colbase, c2 = 128 + colbase;
                    int a1 = fidx(Mt, c1 >> 5, (c1 >> 3) & 3, ln, 6) + (c1 & 7);
                    int a2 = fidx(Mt, c2 >> 5, (c2 >> 3) & 3, ln, 6) + (c2 & 7);
                    ushort hHv[4], u0[4], u1[4], u2[4], ov[4];
                    *(uint2*)hHv = *(const uint2*)&s_hH[aH];
                    *(uint2*)u0 = *(const uint2*)&s_hhu[a0];
                    *(uint2*)u1 = *(const uint2*)&s_hhu[a1];
                    *(uint2*)u2 = *(const uint2*)&s_hhu[a2];
                    float of[4];
#pragma unroll
                    for (int r = 0; r < 4; ++r) {
                        float e0 = fexp2(azg[0][r] + bz0[r]);
                        float e1 = fexp2(azg[1][r] + bz1[r]);
                        float e2 = fexp2(azg[2][r] + bz2[r]);
                        float e3 = fexp2(azg[3][r] + bz3[r]);
                        float inv = frcp(e0 + e1 + e2 + e3);
                        float v = (e0 * bfr2f(hHv[r]) + e1 * bfr2f(u0[r]) +
                                   e2 * bfr2f(u1[r]) + e3 * bfr2f(u2[r])) * inv;
                        ov[r] = f2bfr(v); of[r] = v;
                    }
                    *(uint2*)&s_t[row * OSTR + colbase] = *(const uint2*)ov;
                    if (outp)
                        *(float4*)&outp[(size_t)(row0 + row) * 64 + colbase] = *(const float4*)of;
                }
            }
        }
    }
    __syncthreads();
    {
        const int tid2 = threadIdx.x;
#pragma unroll
        for (int it = 0; it < 2; ++it) {
            int idx = it * 256 + tid2;
            int row = idx >> 3, ck = idx & 7;
            if (row < rows)
                *(uint4*)&u_io[(size_t)(row0 + row) * 64 + ck * 8] =
                    *(const uint4*)&s_t[row * OSTR + ck * 8];
        }
    }
}

// j=8..3, B=512 blocks (2/CU co-resident: 57KB LDS x2 <= 160KB, ~236 VGPR x2
// waves <= 512/SIMD). Nested slices valid down to j=3 (R_j >= B).
__global__ __launch_bounds__(256, 1) void fused_mid_regs(
    const float* __restrict__ contents, bfr* __restrict__ u_all,
    const bfr* __restrict__ wr, const float* __restrict__ brs,
    const bfr* __restrict__ wh, const float* __restrict__ b_h,
    const bfr* __restrict__ wz, const float* __restrict__ bzs,
    const bfr* __restrict__ wu, const float* __restrict__ b_u)
{
    __shared__ bfr s_hhu[12288];
    __shared__ bfr s_t[12288];
    __shared__ bfr s_hH[4096];
    const int tid = threadIdx.x;
    const int lane = tid & 63, w = tid >> 6, ln = lane & 15, q = lane >> 4;
    bf16x8 Af[3][6], Ah[6], Aw[4][8], awu;
    load_wregs(wr, wh, wz, wu, w, q, ln, Af, Ah, Aw, awu);
    for (int j = 8; j >= 3; --j) {
        int rows = 1 << (j - 3);   // 32..1
        const float* c_own = contents + (size_t)((64 << j) - 64) * 7;
        tile_regs(blockIdx.x * rows, rows,
                  u_all + lvloff(j + 1), c_own, u_all + lvloff(j),
                  awu, b_u, Af, Ah, Aw, brs, b_h, bzs,
                  nullptr, s_hhu, s_t, s_hH);
    }
}

// j=2..0, B=64 blocks (rows 4,2,1; children = own prior writes within kernel).
__global__ __launch_bounds__(256, 1) void fused_tail_regs(
    const float* __restrict__ contents, bfr* __restrict__ u_all,
    const bfr* __restrict__ wr, const float* __restrict__ brs,
    const bfr* __restrict__ wh, const float* __restrict__ b_h,
    const bfr* __restrict__ wz, const float* __restrict__ bzs,
    const bfr* __restrict__ wu, const float* __restrict__ b_u,
    float* __restrict__ outp)
{
    __shared__ bfr s_hhu[12288];
    __shared__ bfr s_t[12288];
    __shared__ bfr s_hH[4096];
    const int tid = threadIdx.x;
    const int lane = tid & 63, w = tid >> 6, ln = lane & 15, q = lane >> 4;
    bf16x8 Af[3][6], Ah[6], Aw[4][8], awu;
    load_wregs(wr, wh, wz, wu, w, q, ln, Af, Ah, Aw, awu);
    for (int j = 2; j >= 0; --j) {
        int rows = 1 << j;         // 4, 2, 1
        const float* c_own = contents + (size_t)((64 << j) - 64) * 7;
        tile_regs(blockIdx.x * rows, rows,
                  u_all + lvloff(j + 1), c_own, u_all + lvloff(j),
                  awu, b_u, Af, Ah, Aw, brs, b_h, bzs,
                  (j == 0) ? outp : nullptr, s_hhu, s_t, s_hH);
    }
}

extern "C" void kernel_launch(void* const* d_in, const int* in_sizes, int n_in,
                              void* d_out, int out_size, void* d_ws, size_t ws_size,
                              hipStream_t stream) {
    const float* contents = (const float*)d_in[0];
    const float* W_u = (const float*)d_in[1];
    const float* b_u = (const float*)d_in[2];
    const float* W_r = (const float*)d_in[3];
    const float* b_r = (const float*)d_in[4];
    const float* W_h = (const float*)d_in[5];
    const float* b_h = (const float*)d_in[6];
    const float* W_z = (const float*)d_in[7];
    const float* b_z = (const float*)d_in[8];
    float* out = (float*)d_out;

    // ws: u_all up-regions | packed weights | scaled biases
    bfr* u_all = (bfr*)d_ws;
    bfr* wr = u_all + (size_t)524224 * 64;
    bfr* wh = wr + 36864;
    bfr* wz = wh + 12288;
    float* brs = (float*)(wz + 65536);
    float* bzs = brs + 192;
    bfr* wu = (bfr*)(bzs + 256);

    convert_weights<<<256, 256, 0, stream>>>(W_r, W_h, W_z, W_u, b_r, b_z,
                                             wr, wh, wz, wu, brs, bzs);

    const float* c12 = contents + (size_t)((64 << 12) - 64) * 7;
    const float* c11 = contents + (size_t)((64 << 11) - 64) * 7;
    const float* c10 = contents + (size_t)((64 << 10) - 64) * 7;
    const float* c9  = contents + (size_t)((64 << 9) - 64) * 7;

    level11_kernel<<<2048, 256, 0, stream>>>(c12, c11, u_all + lvloff(11),
                                             wr, brs, wh, b_h, wz, bzs, wu, b_u);
    level_kernel<<<1024, 256, 0, stream>>>(u_all + lvloff(11), c10, u_all + lvloff(10),
                                           wr, brs, wh, b_h, wz, bzs, wu, b_u);
    level_kernel<<<512, 256, 0, stream>>>(u_all + lvloff(10), c9, u_all + lvloff(9),
                                          wr, brs, wh, b_h, wz, bzs, wu, b_u);
    fused_mid_regs<<<512, 256, 0, stream>>>(contents, u_all,
                                            wr, brs, wh, b_h, wz, bzs, wu, b_u);
    fused_tail_regs<<<64, 256, 0, stream>>>(contents, u_all,
                                            wr, brs, wh, b_h, wz, bzs, wu, b_u, out);
}

// Round 21
// 195.132 us; speedup vs baseline: 1.0628x; 1.0628x over previous
//
#include <hip/hip_runtime.h>
#include <hip/hip_bf16.h>

// GRNNTransformGated, round 20: FINAL — restore measured-best (R17, 198us).
// Post-mortem ledger (final):
//  R4: agent-scope spin grid barriers ~137us each -> never.
//  R12: (256,3) spilled mm3's az[4][4] (VGPR 84, WRITE 96-340MB scratch).
//      (256,2) clean. RULE: VGPR below live-acc arithmetic == spill;
//      WRITE_SIZE >> data written is the tell.
//  R13/R14: fusing big levels at low occupancy loses; occupancy > weight
//      persistence; tiles below 64 rows cost full-tile latency.
//  R15: +8KB LDS cost a block/CU on big levels; fused (256,1) gained from
//      separate s_hH (occupancy fixed at 1 block anyway).
//  R16: per-lane direct c loads on the MFMA dep chain in the glob tile ->
//      regression; cooperative staging + barrier wins.
//  R17/R18: 198us plateau (12.9x over round-1 baseline); bare launch-bounds
//      neutral. R19: B=512 fused chain regressed (~+24us).
//  STRUCTURAL FLOOR: 13 strictly sequential levels x multi-barrier tile
//      critical path; pipes <35%, HBM <5%, no spill. Further gains need a
//      different decomposition (wave-specialized cross-level pipelining),
//      not tuning.
// Carried: in-place up regions in u_all; exp2-folded W_r/b_r/W_z/b_z;
// operand-swapped MFMA (D = W @ act^T; lane gets 4 consecutive out-cols of
// one row -> b64 epilogues); coalesced up-store via LDS round-trip; MFMA-u;
// j=11 computes level-12 children u from contents (u12 never materialized).

#define LOG2E 1.4426950408889634f
#define OSTR 76   // out-staging row stride (elements)

typedef __bf16 bf16x8 __attribute__((ext_vector_type(8)));
typedef unsigned short u16x8 __attribute__((ext_vector_type(8)));
typedef float f32x4 __attribute__((ext_vector_type(4)));
typedef unsigned short bfr;   // raw bf16 bits

__device__ __forceinline__ float bfr2f(bfr v) { return __uint_as_float(((unsigned)v) << 16); }
__device__ __forceinline__ bfr f2bfr(float f) {
    __hip_bfloat16 h = __float2bfloat16(f);
    return __builtin_bit_cast(bfr, h);
}
__device__ __forceinline__ float fexp2(float x) {
#if __has_builtin(__builtin_amdgcn_exp2f)
    return __builtin_amdgcn_exp2f(x);
#else
    return exp2f(x);
#endif
}
__device__ __forceinline__ float frcp(float x) {
#if __has_builtin(__builtin_amdgcn_rcpf)
    return __builtin_amdgcn_rcpf(x);
#else
    return 1.f / x;
#endif
}

// fragment-order address (elements): frag (Mt,kt), lane (ln,q), 8 elems
__device__ __forceinline__ int fidx(int Mt, int kt, int q, int ln, int KT) {
    return ((((Mt * KT + kt) * 4 + q) * 16 + ln) * 8);
}

// level-j up region start (elements) within u_all
__device__ __host__ __forceinline__ size_t lvloff(int j) {
    return (size_t)((64 << j) - 64) * 64;
}

__device__ __forceinline__ void pack_one(const float* __restrict__ W, bfr* __restrict__ dst,
                                         int d, int K, float scale) {
    int KT = K >> 5;
    int j = d & 7, lnc = (d >> 3) & 15, q = (d >> 7) & 3;
    int t1 = d >> 9;
    int kt = t1 % KT, ntile = t1 / KT;
    int ncol = ntile * 16 + lnc;
    int k = kt * 32 + q * 8 + j;
    dst[d] = f2bfr(W[(size_t)ncol * K + k] * scale);
}

__global__ void convert_weights(const float* __restrict__ Wr, const float* __restrict__ Wh,
                                const float* __restrict__ Wz, const float* __restrict__ Wu,
                                const float* __restrict__ br, const float* __restrict__ bz,
                                bfr* __restrict__ wr, bfr* __restrict__ wh, bfr* __restrict__ wz,
                                bfr* __restrict__ wu,
                                float* __restrict__ brs, float* __restrict__ bzs) {
    int i = blockIdx.x * 256 + threadIdx.x;   // grid covers 65536
    if (i < 36864) pack_one(Wr, wr, i, 192, LOG2E);
    if (i < 12288) pack_one(Wh, wh, i, 192, 1.f);
    if (i < 65536) pack_one(Wz, wz, i, 256, LOG2E);
    if (i < 2048) {   // W_u (64x7) -> frag order K=32, zero-padded
        int j = i & 7, lnc = (i >> 3) & 15, q = (i >> 7) & 3, ntile = i >> 9;
        int k = q * 8 + j, ncol = ntile * 16 + lnc;
        wu[i] = (k < 7) ? f2bfr(Wu[ncol * 7 + k]) : (bfr)0;
    }
    if (i < 192) brs[i] = br[i] * LOG2E;
    if (i < 256) bzs[i] = bz[i] * LOG2E;
}

// Stage `rows` contents rows (7 f32 each) as bf16 B-frags (K=32 padded).
__device__ __forceinline__ void stage_c(const float* __restrict__ csrc, int rows,
                                        bfr* s_c) {
    const int tid = threadIdx.x;
    for (int t = tid; t < rows * 4; t += 256) {
        int row = t >> 2, qg = t & 3;
        ushort v[8] = {0, 0, 0, 0, 0, 0, 0, 0};
        if (qg == 0) {
            const float* cp = csrc + (size_t)row * 7;
#pragma unroll
            for (int k = 0; k < 7; ++k) v[k] = f2bfr(cp[k]);
        }
        *(uint4*)&s_c[(((row >> 4) * 4 + qg) * 16 + (row & 15)) * 8] = *(const uint4*)v;
    }
}

// Build a contents B-fragment directly from global (q==0 lanes hold k=0..6).
// Used ONLY in the (256,1) fused tiles (R16: hurts the glob tile).
__device__ __forceinline__ bf16x8 load_c_frag(const float* __restrict__ c,
                                              size_t grow, bool active) {
    u16x8 cv = {0, 0, 0, 0, 0, 0, 0, 0};
    if (active) {
        const float* cp = c + grow * 7;
#pragma unroll
        for (int k = 0; k < 7; ++k) cv[k] = f2bfr(cp[k]);
    }
    return __builtin_bit_cast(bf16x8, cv);
}

// Coalesced up-store epilogue via LDS round-trip (R12 form, internal syncs).
__device__ __forceinline__ void store_up_coalesced(
    int row0, int rows, bfr* __restrict__ u_io,
    const ushort (&ovv)[4][4], int Mtn, bfr* s_t)
{
    const int tid = threadIdx.x;
    const int lane = tid & 63, w = tid >> 6;
    const int ln = lane & 15, q = lane >> 4;
    const int colbase = w * 16 + q * 4;
    __syncthreads();
#pragma unroll
    for (int Mt = 0; Mt < 4; ++Mt) {
        if (Mt < Mtn) {
            int row = Mt * 16 + ln;
            if (row < rows)
                *(uint2*)&s_t[row * OSTR + colbase] = *(const uint2*)ovv[Mt];
        }
    }
    __syncthreads();
#pragma unroll
    for (int it = 0; it < 2; ++it) {
        int idx = it * 256 + tid;
        int row = idx >> 3, ck = idx & 7;
        if (row < rows)
            *(uint4*)&u_io[(size_t)(row0 + row) * 64 + ck * 8] =
                *(const uint4*)&s_t[row * OSTR + ck * 8];
    }
}

// mm_u: u = relu(c @ W_u^T) via MFMA from staged c frags into s_hhu (kt4..5).
__device__ __forceinline__ void mmu_own(const bfr* s_c, bfr* s_hhu, bf16x8 awu,
                                        f32x4 bu4, int Mtn, int ln, int q,
                                        int colbase) {
#pragma unroll
    for (int Mt = 0; Mt < 4; ++Mt) {
        if (Mt < Mtn) {
            bf16x8 Bc = *(const bf16x8*)&s_c[((Mt * 4 + q) * 16 + ln) * 8];
            f32x4 acc = {0.f, 0.f, 0.f, 0.f};
            acc = __builtin_amdgcn_mfma_f32_16x16x32_bf16(awu, Bc, acc, 0, 0, 0);
            int kk = 128 + colbase;
            int addr = fidx(Mt, kk >> 5, (kk >> 3) & 3, ln, 6) + (kk & 7);
            ushort uv[4];
#pragma unroll
            for (int r = 0; r < 4; ++r) uv[r] = f2bfr(fmaxf(acc[r] + bu4[r], 0.f));
            *(uint2*)&s_hhu[addr] = *(const uint2*)uv;
        }
    }
}

// ============ glob tile (R12/R17): per-phase L2 weight loads, 48KB =========
template <bool CHILD_U>
__device__ __forceinline__ void tile_glob(
    int row0,
    const bfr* __restrict__ ch, const float* __restrict__ c_child,
    const float* __restrict__ c_own, bfr* __restrict__ u_io,
    const bfr* __restrict__ wu, const float* __restrict__ b_u,
    const bfr* __restrict__ wr, const float* __restrict__ brs,
    const bfr* __restrict__ wh, const float* __restrict__ b_h,
    const bfr* __restrict__ wz, const float* __restrict__ bzs,
    bfr* s_hhu, bfr* s_t)
{
    bfr* s_hH = s_t;   // alias: h_H written only after all t reads done
    const int tid = threadIdx.x;
    const int lane = tid & 63, w = tid >> 6;
    const int ln = lane & 15, q = lane >> 4;
    const int colbase = w * 16 + q * 4;

    // ---- stage children + own contents (cooperative) ----
    if (!CHILD_U) {
#pragma unroll
        for (int it = 0; it < 4; ++it) {
            int idx = it * 256 + tid;
            int lns = idx & 15, qs = (idx >> 4) & 3, kts = (idx >> 6) & 3, Mts = idx >> 8;
            int row = Mts * 16 + lns;
            int k = kts * 32 + qs * 8;
            const bfr* src = (k < 64)
                ? ch + (size_t)(2 * (row0 + row)) * 64 + k
                : ch + (size_t)(2 * (row0 + row) + 1) * 64 + (k - 64);
            *(uint4*)&s_hhu[fidx(Mts, kts, qs, lns, 6)] = *(const uint4*)src;
        }
    } else {
        stage_c(c_child + (size_t)(2 * row0) * 7, 128, s_t + 2048);
    }
    stage_c(c_own + (size_t)row0 * 7, 64, s_t);
    __syncthreads();

    // ---- mm_u ----
    {
        bf16x8 awu = *(const bf16x8*)&wu[fidx(w, 0, q, ln, 1)];
        f32x4 bu4 = *(const f32x4*)&b_u[colbase];
        if (CHILD_U) {
#pragma unroll
            for (int Mt = 0; Mt < 8; ++Mt) {
                bf16x8 Bc = *(const bf16x8*)&s_t[2048 + (((Mt * 4 + q) * 16 + ln) * 8)];
                f32x4 acc = {0.f, 0.f, 0.f, 0.f};
                acc = __builtin_amdgcn_mfma_f32_16x16x32_bf16(awu, Bc, acc, 0, 0, 0);
                int crow = Mt * 16 + ln;
                int row = crow >> 1;
                int kk = (crow & 1) * 64 + colbase;
                int addr = fidx(row >> 4, kk >> 5, (kk >> 3) & 3, row & 15, 6) + (kk & 7);
                ushort uv[4];
#pragma unroll
                for (int r = 0; r < 4; ++r) uv[r] = f2bfr(fmaxf(acc[r] + bu4[r], 0.f));
                *(uint2*)&s_hhu[addr] = *(const uint2*)uv;
            }
        }
        mmu_own(s_t, s_hhu, awu, bu4, 4, ln, q, colbase);
    }
    __syncthreads();

    // ---- mm1 ----
    {
        bf16x8 Af[3][6];
#pragma unroll
        for (int nt = 0; nt < 3; ++nt)
#pragma unroll
            for (int kt = 0; kt < 6; ++kt)
                Af[nt][kt] = *(const bf16x8*)&wr[fidx(w * 3 + nt, kt, q, ln, 6)];
#pragma unroll
        for (int Mt = 0; Mt < 4; ++Mt) {
            bf16x8 Bf[6];
#pragma unroll
            for (int kt = 0; kt < 6; ++kt)
                Bf[kt] = *(const bf16x8*)&s_hhu[fidx(Mt, kt, q, ln, 6)];
#pragma unroll
            for (int nt = 0; nt < 3; ++nt) {
                int cb1 = (w * 3 + nt) * 16 + q * 4;
                f32x4 acc = {0.f, 0.f, 0.f, 0.f};
#pragma unroll
                for (int kt = 0; kt < 6; ++kt)
                    acc = __builtin_amdgcn_mfma_f32_16x16x32_bf16(Af[nt][kt], Bf[kt], acc, 0, 0, 0);
                f32x4 br4 = *(const f32x4*)&brs[cb1];
                int addr = fidx(Mt, cb1 >> 5, (cb1 >> 3) & 3, ln, 6) + (cb1 & 7);
                ushort hh[4], tt[4];
                *(uint2*)hh = *(const uint2*)&s_hhu[addr];
#pragma unroll
                for (int r = 0; r < 4; ++r) {
                    float e = fexp2(-(acc[r] + br4[r]));
                    tt[r] = f2bfr(frcp(1.f + e) * bfr2f(hh[r]));
                }
                *(uint2*)&s_t[addr] = *(const uint2*)tt;
            }
        }
    }
    __syncthreads();

    // ---- mm2: acc in regs; after all t reads, write aliased s_hH ----
    f32x4 hacc[4];
    {
        bf16x8 Ah[6];
#pragma unroll
        for (int kt = 0; kt < 6; ++kt)
            Ah[kt] = *(const bf16x8*)&wh[fidx(w, kt, q, ln, 6)];
#pragma unroll
        for (int Mt = 0; Mt < 4; ++Mt) {
            f32x4 acc = {0.f, 0.f, 0.f, 0.f};
#pragma unroll
            for (int kt = 0; kt < 6; ++kt) {
                bf16x8 Bf = *(const bf16x8*)&s_t[fidx(Mt, kt, q, ln, 6)];
                acc = __builtin_amdgcn_mfma_f32_16x16x32_bf16(Ah[kt], Bf, acc, 0, 0, 0);
            }
            hacc[Mt] = acc;
        }
    }
    __syncthreads();
    {
        f32x4 bh4 = *(const f32x4*)&b_h[colbase];
#pragma unroll
        for (int Mt = 0; Mt < 4; ++Mt) {
            int addr = fidx(Mt, colbase >> 5, (colbase >> 3) & 3, ln, 2) + (colbase & 7);
            ushort hv[4];
#pragma unroll
            for (int r = 0; r < 4; ++r) hv[r] = f2bfr(fmaxf(hacc[Mt][r] + bh4[r], 0.f));
            *(uint2*)&s_hH[addr] = *(const uint2*)hv;
        }
    }
    __syncthreads();

    // ---- mm3 (g-outer, az[4][4] resident) + gate ----
    {
        f32x4 az[4][4];
#pragma unroll
        for (int Mt = 0; Mt < 4; ++Mt)
#pragma unroll
            for (int g = 0; g < 4; ++g) az[Mt][g] = (f32x4){0.f, 0.f, 0.f, 0.f};
#pragma unroll
        for (int g = 0; g < 4; ++g) {
            bf16x8 Aw[8];
#pragma unroll
            for (int kt = 0; kt < 8; ++kt)
                Aw[kt] = *(const bf16x8*)&wz[fidx(g * 4 + w, kt, q, ln, 8)];
#pragma unroll
            for (int Mt = 0; Mt < 4; ++Mt) {
                f32x4 acc = az[Mt][g];
                acc = __builtin_amdgcn_mfma_f32_16x16x32_bf16(
                    Aw[0], *(const bf16x8*)&s_hH[fidx(Mt, 0, q, ln, 2)], acc, 0, 0, 0);
                acc = __builtin_amdgcn_mfma_f32_16x16x32_bf16(
                    Aw[1], *(const bf16x8*)&s_hH[fidx(Mt, 1, q, ln, 2)], acc, 0, 0, 0);
#pragma unroll
                for (int kt = 0; kt < 6; ++kt)
                    acc = __builtin_amdgcn_mfma_f32_16x16x32_bf16(
                        Aw[2 + kt], *(const bf16x8*)&s_hhu[fidx(Mt, kt, q, ln, 6)], acc, 0, 0, 0);
                az[Mt][g] = acc;
            }
        }
        f32x4 bz0 = *(const f32x4*)&bzs[colbase];
        f32x4 bz1 = *(const f32x4*)&bzs[64 + colbase];
        f32x4 bz2 = *(const f32x4*)&bzs[128 + colbase];
        f32x4 bz3 = *(const f32x4*)&bzs[192 + colbase];
        ushort ovv[4][4];
#pragma unroll
        for (int Mt = 0; Mt < 4; ++Mt) {
            int aH = fidx(Mt, colbase >> 5, (colbase >> 3) & 3, ln, 2) + (colbase & 7);
            int a0 = fidx(Mt, colbase >> 5, (colbase >> 3) & 3, ln, 6) + (colbase & 7);
            int c1 = 64 + colbase, c2 = 128 + colbase;
            int a1 = fidx(Mt, c1 >> 5, (c1 >> 3) & 3, ln, 6) + (c1 & 7);
            int a2 = fidx(Mt, c2 >> 5, (c2 >> 3) & 3, ln, 6) + (c2 & 7);
            ushort hHv[4], u0[4], u1[4], u2[4];
            *(uint2*)hHv = *(const uint2*)&s_hH[aH];
            *(uint2*)u0 = *(const uint2*)&s_hhu[a0];
            *(uint2*)u1 = *(const uint2*)&s_hhu[a1];
            *(uint2*)u2 = *(const uint2*)&s_hhu[a2];
#pragma unroll
            for (int r = 0; r < 4; ++r) {
                float e0 = fexp2(az[Mt][0][r] + bz0[r]);
                float e1 = fexp2(az[Mt][1][r] + bz1[r]);
                float e2 = fexp2(az[Mt][2][r] + bz2[r]);
                float e3 = fexp2(az[Mt][3][r] + bz3[r]);
                float inv = frcp(e0 + e1 + e2 + e3);
                float v = (e0 * bfr2f(hHv[r]) + e1 * bfr2f(u0[r]) +
                           e2 * bfr2f(u1[r]) + e3 * bfr2f(u2[r])) * inv;
                ovv[Mt][r] = f2bfr(v);
            }
        }
        store_up_coalesced(row0, 64, u_io, ovv, 4, s_t);
    }
}

__global__ __launch_bounds__(256, 2) void level11_kernel(
    const float* __restrict__ c12, const float* __restrict__ c11,
    bfr* __restrict__ u_io,
    const bfr* __restrict__ wr, const float* __restrict__ brs,
    const bfr* __restrict__ wh, const float* __restrict__ b_h,
    const bfr* __restrict__ wz, const float* __restrict__ bzs,
    const bfr* __restrict__ wu, const float* __restrict__ b_u)
{
    __shared__ bfr s_hhu[12288];
    __shared__ bfr s_t[12288];
    tile_glob<true>(blockIdx.x * 64, nullptr, c12, c11, u_io,
                    wu, b_u, wr, brs, wh, b_h, wz, bzs, s_hhu, s_t);
}

__global__ __launch_bounds__(256, 2) void level_kernel(
    const bfr* __restrict__ ch, const float* __restrict__ c_own,
    bfr* __restrict__ u_io,
    const bfr* __restrict__ wr, const float* __restrict__ brs,
    const bfr* __restrict__ wh, const float* __restrict__ b_h,
    const bfr* __restrict__ wz, const float* __restrict__ bzs,
    const bfr* __restrict__ wu, const float* __restrict__ b_u)
{
    __shared__ bfr s_hhu[12288];
    __shared__ bfr s_t[12288];
    tile_glob<false>(blockIdx.x * 64, ch, nullptr, c_own, u_io,
                     wu, b_u, wr, brs, wh, b_h, wz, bzs, s_hhu, s_t);
}

// ========= fused (256,1) variant: register-persistent weights (R15) ========
__device__ __forceinline__ void load_wregs(
    const bfr* __restrict__ wr, const bfr* __restrict__ wh, const bfr* __restrict__ wz,
    const bfr* __restrict__ wu, int w, int q, int ln,
    bf16x8 (&Af)[3][6], bf16x8 (&Ah)[6], bf16x8 (&Aw)[4][8], bf16x8& awu)
{
#pragma unroll
    for (int nt = 0; nt < 3; ++nt)
#pragma unroll
        for (int kt = 0; kt < 6; ++kt)
            Af[nt][kt] = *(const bf16x8*)&wr[fidx(w * 3 + nt, kt, q, ln, 6)];
#pragma unroll
    for (int kt = 0; kt < 6; ++kt)
        Ah[kt] = *(const bf16x8*)&wh[fidx(w, kt, q, ln, 6)];
#pragma unroll
    for (int g = 0; g < 4; ++g)
#pragma unroll
        for (int kt = 0; kt < 8; ++kt)
            Aw[g][kt] = *(const bf16x8*)&wz[fidx(g * 4 + w, kt, q, ln, 8)];
    awu = *(const bf16x8*)&wu[fidx(w, 0, q, ln, 1)];
}

__device__ __forceinline__ void tile_regs(
    int row0, int rows,
    const bfr* __restrict__ ch, const float* __restrict__ c_own,
    bfr* __restrict__ u_io,
    const bf16x8 awu, const float* __restrict__ b_u,
    const bf16x8 (&Af)[3][6], const bf16x8 (&Ah)[6], const bf16x8 (&Aw)[4][8],
    const float* __restrict__ brs, const float* __restrict__ b_h,
    const float* __restrict__ bzs,
    float* __restrict__ outp, bfr* s_hhu, bfr* s_t, bfr* s_hH)
{
    const int tid = threadIdx.x;
    const int lane = tid & 63, w = tid >> 6;
    const int ln = lane & 15, q = lane >> 4;
    const int Mtn = (rows + 15) >> 4;
    const int colbase = w * 16 + q * 4;

    __syncthreads();   // chain: prior coop-store reads + global visibility

    // ---- phase A ----
#pragma unroll
    for (int it = 0; it < 4; ++it) {
        int idx = it * 256 + tid;
        int lns = idx & 15, qs = (idx >> 4) & 3, kts = (idx >> 6) & 3, Mts = idx >> 8;
        int row = Mts * 16 + lns;
        if (row < rows) {
            int k = kts * 32 + qs * 8;
            const bfr* src = (k < 64)
                ? ch + (size_t)(2 * (row0 + row)) * 64 + k
                : ch + (size_t)(2 * (row0 + row) + 1) * 64 + (k - 64);
            *(uint4*)&s_hhu[fidx(Mts, kts, qs, lns, 6)] = *(const uint4*)src;
        }
    }
    {
        f32x4 bu4 = *(const f32x4*)&b_u[colbase];
#pragma unroll
        for (int Mt = 0; Mt < 4; ++Mt) {
            if (Mt < Mtn) {
                int row = Mt * 16 + ln;
                bf16x8 Bc = load_c_frag(c_own, (size_t)row0 + row, q == 0 && row < rows);
                f32x4 acc = {0.f, 0.f, 0.f, 0.f};
                acc = __builtin_amdgcn_mfma_f32_16x16x32_bf16(awu, Bc, acc, 0, 0, 0);
                int kk = 128 + colbase;
                int addr = fidx(Mt, kk >> 5, (kk >> 3) & 3, ln, 6) + (kk & 7);
                ushort uv[4];
#pragma unroll
                for (int r = 0; r < 4; ++r) uv[r] = f2bfr(fmaxf(acc[r] + bu4[r], 0.f));
                *(uint2*)&s_hhu[addr] = *(const uint2*)uv;
            }
        }
    }
    __syncthreads();

    // ---- mm1 ----
#pragma unroll
    for (int Mt = 0; Mt < 4; ++Mt) {
        if (Mt < Mtn) {
            bf16x8 Bf[6];
#pragma unroll
            for (int kt = 0; kt < 6; ++kt)
                Bf[kt] = *(const bf16x8*)&s_hhu[fidx(Mt, kt, q, ln, 6)];
#pragma unroll
            for (int nt = 0; nt < 3; ++nt) {
                int cb1 = (w * 3 + nt) * 16 + q * 4;
                f32x4 acc = {0.f, 0.f, 0.f, 0.f};
#pragma unroll
                for (int kt = 0; kt < 6; ++kt)
                    acc = __builtin_amdgcn_mfma_f32_16x16x32_bf16(Af[nt][kt], Bf[kt], acc, 0, 0, 0);
                f32x4 br4 = *(const f32x4*)&brs[cb1];
                int addr = fidx(Mt, cb1 >> 5, (cb1 >> 3) & 3, ln, 6) + (cb1 & 7);
                ushort hh[4], tt[4];
                *(uint2*)hh = *(const uint2*)&s_hhu[addr];
#pragma unroll
                for (int r = 0; r < 4; ++r) {
                    float e = fexp2(-(acc[r] + br4[r]));
                    tt[r] = f2bfr(frcp(1.f + e) * bfr2f(hh[r]));
                }
                *(uint2*)&s_t[addr] = *(const uint2*)tt;
            }
        }
    }
    __syncthreads();

    // ---- mm2 -> s_hH direct (separate region) ----
    {
        f32x4 bh4 = *(const f32x4*)&b_h[colbase];
#pragma unroll
        for (int Mt = 0; Mt < 4; ++Mt) {
            if (Mt < Mtn) {
                f32x4 acc = {0.f, 0.f, 0.f, 0.f};
#pragma unroll
                for (int kt = 0; kt < 6; ++kt) {
                    bf16x8 Bf = *(const bf16x8*)&s_t[fidx(Mt, kt, q, ln, 6)];
                    acc = __builtin_amdgcn_mfma_f32_16x16x32_bf16(Ah[kt], Bf, acc, 0, 0, 0);
                }
                int addr = fidx(Mt, colbase >> 5, (colbase >> 3) & 3, ln, 2) + (colbase & 7);
                ushort hv[4];
#pragma unroll
                for (int r = 0; r < 4; ++r) hv[r] = f2bfr(fmaxf(acc[r] + bh4[r], 0.f));
                *(uint2*)&s_hH[addr] = *(const uint2*)hv;
            }
        }
    }
    __syncthreads();

    // ---- mm3 per-Mt + gate -> stage rows in s_t ----
    {
        f32x4 bz0 = *(const f32x4*)&bzs[colbase];
        f32x4 bz1 = *(const f32x4*)&bzs[64 + colbase];
        f32x4 bz2 = *(const f32x4*)&bzs[128 + colbase];
        f32x4 bz3 = *(const f32x4*)&bzs[192 + colbase];
#pragma unroll
        for (int Mt = 0; Mt < 4; ++Mt) {
            if (Mt < Mtn) {
                bf16x8 Az[8];
                Az[0] = *(const bf16x8*)&s_hH[fidx(Mt, 0, q, ln, 2)];
                Az[1] = *(const bf16x8*)&s_hH[fidx(Mt, 1, q, ln, 2)];
#pragma unroll
                for (int kt = 0; kt < 6; ++kt)
                    Az[2 + kt] = *(const bf16x8*)&s_hhu[fidx(Mt, kt, q, ln, 6)];
                f32x4 azg[4];
#pragma unroll
                for (int g = 0; g < 4; ++g) {
                    f32x4 acc = {0.f, 0.f, 0.f, 0.f};
#pragma unroll
                    for (int kt = 0; kt < 8; ++kt)
                        acc = __builtin_amdgcn_mfma_f32_16x16x32_bf16(Aw[g][kt], Az[kt], acc, 0, 0, 0);
                    azg[g] = acc;
                }
                int row = Mt * 16 + ln;
                if (row < rows) {
                    int aH = fidx(Mt, colbase >> 5, (colbase >> 3) & 3, ln, 2) + (colbase & 7);
                    int a0 = fidx(Mt, colbase >> 5, (colbase >> 3) & 3, ln, 6) + (colbase & 7);
                    int c1 = 64 + colbase, c2 = 128 + colbase;
                    int a1 = fidx(Mt, c1 >> 5, (c1 >> 3) & 3, ln, 6) + (c1 & 7);
                    int a2 = fidx(Mt, c2 >> 5, (c2 >> 3) & 3, ln, 6) + (c2 & 7);
                    ushort hHv[4], u0[4], u1[4], u2[4], ov[4];
                    *(uint2*)hHv = *(const uint2*)&s_hH[aH];
                    *(uint2*)u0 = *(const uint2*)&s_hhu[a0];
                    *(uint2*)u1 = *(const uint2*)&s_hhu[a1];
                    *(uint2*)u2 = *(const uint2*)&s_hhu[a2];
                    float of[4];
#pragma unroll
                    for (int r = 0; r < 4; ++r) {
                        float e0 = fexp2(azg[0][r] + bz0[r]);
                        float e1 = fexp2(azg[1][r] + bz1[r]);
                        float e2 = fexp2(azg[2][r] + bz2[r]);
                        float e3 = fexp2(azg[3][r] + bz3[r]);
                        float inv = frcp(e0 + e1 + e2 + e3);
                        float v = (e0 * bfr2f(hHv[r]) + e1 * bfr2f(u0[r]) +
                                   e2 * bfr2f(u1[r]) + e3 * bfr2f(u2[r])) * inv;
                        ov[r] = f2bfr(v); of[r] = v;
                    }
                    *(uint2*)&s_t[row * OSTR + colbase] = *(const uint2*)ov;
                    if (outp)
                        *(float4*)&outp[(size_t)(row0 + row) * 64 + colbase] = *(const float4*)of;
                }
            }
        }
    }
    __syncthreads();
    {
        const int tid2 = threadIdx.x;
#pragma unroll
        for (int it = 0; it < 2; ++it) {
            int idx = it * 256 + tid2;
            int row = idx >> 3, ck = idx & 7;
            if (row < rows)
                *(uint4*)&u_io[(size_t)(row0 + row) * 64 + ck * 8] =
                    *(const uint4*)&s_t[row * OSTR + ck * 8];
        }
    }
}

// j=8..2, B=256 blocks; register-persistent weights; nested slices.
__global__ __launch_bounds__(256, 1) void fused_mid_regs(
    const float* __restrict__ contents, bfr* __restrict__ u_all,
    const bfr* __restrict__ wr, const float* __restrict__ brs,
    const bfr* __restrict__ wh, const float* __restrict__ b_h,
    const bfr* __restrict__ wz, const float* __restrict__ bzs,
    const bfr* __restrict__ wu, const float* __restrict__ b_u)
{
    __shared__ bfr s_hhu[12288];
    __shared__ bfr s_t[12288];
    __shared__ bfr s_hH[4096];
    const int tid = threadIdx.x;
    const int lane = tid & 63, w = tid >> 6, ln = lane & 15, q = lane >> 4;
    bf16x8 Af[3][6], Ah[6], Aw[4][8], awu;
    load_wregs(wr, wh, wz, wu, w, q, ln, Af, Ah, Aw, awu);
    for (int j = 8; j >= 2; --j) {
        int rows = 1 << (j - 2);   // 64..1
        const float* c_own = contents + (size_t)((64 << j) - 64) * 7;
        tile_regs(blockIdx.x * rows, rows,
                  u_all + lvloff(j + 1), c_own, u_all + lvloff(j),
                  awu, b_u, Af, Ah, Aw, brs, b_h, bzs,
                  nullptr, s_hhu, s_t, s_hH);
    }
}

// j=1..0, B=64 blocks.
__global__ __launch_bounds__(256, 1) void fused_tail_regs(
    const float* __restrict__ contents, bfr* __restrict__ u_all,
    const bfr* __restrict__ wr, const float* __restrict__ brs,
    const bfr* __restrict__ wh, const float* __restrict__ b_h,
    const bfr* __restrict__ wz, const float* __restrict__ bzs,
    const bfr* __restrict__ wu, const float* __restrict__ b_u,
    float* __restrict__ outp)
{
    __shared__ bfr s_hhu[12288];
    __shared__ bfr s_t[12288];
    __shared__ bfr s_hH[4096];
    const int tid = threadIdx.x;
    const int lane = tid & 63, w = tid >> 6, ln = lane & 15, q = lane >> 4;
    bf16x8 Af[3][6], Ah[6], Aw[4][8], awu;
    load_wregs(wr, wh, wz, wu, w, q, ln, Af, Ah, Aw, awu);
    for (int j = 1; j >= 0; --j) {
        int rows = 1 << j;         // 2, 1
        const float* c_own = contents + (size_t)((64 << j) - 64) * 7;
        tile_regs(blockIdx.x * rows, rows,
                  u_all + lvloff(j + 1), c_own, u_all + lvloff(j),
                  awu, b_u, Af, Ah, Aw, brs, b_h, bzs,
                  (j == 0) ? outp : nullptr, s_hhu, s_t, s_hH);
    }
}

extern "C" void kernel_launch(void* const* d_in, const int* in_sizes, int n_in,
                              void* d_out, int out_size, void* d_ws, size_t ws_size,
                              hipStream_t stream) {
    const float* contents = (const float*)d_in[0];
    const float* W_u = (const float*)d_in[1];
    const float* b_u = (const float*)d_in[2];
    const float* W_r = (const float*)d_in[3];
    const float* b_r = (const float*)d_in[4];
    const float* W_h = (const float*)d_in[5];
    const float* b_h = (const float*)d_in[6];
    const float* W_z = (const float*)d_in[7];
    const float* b_z = (const float*)d_in[8];
    float* out = (float*)d_out;

    // ws: u_all up-regions | packed weights | scaled biases
    bfr* u_all = (bfr*)d_ws;
    bfr* wr = u_all + (size_t)524224 * 64;
    bfr* wh = wr + 36864;
    bfr* wz = wh + 12288;
    float* brs = (float*)(wz + 65536);
    float* bzs = brs + 192;
    bfr* wu = (bfr*)(bzs + 256);

    convert_weights<<<256, 256, 0, stream>>>(W_r, W_h, W_z, W_u, b_r, b_z,
                                             wr, wh, wz, wu, brs, bzs);

    const float* c12 = contents + (size_t)((64 << 12) - 64) * 7;
    const float* c11 = contents + (size_t)((64 << 11) - 64) * 7;
    const float* c10 = contents + (size_t)((64 << 10) - 64) * 7;
    const float* c9  = contents + (size_t)((64 << 9) - 64) * 7;

    level11_kernel<<<2048, 256, 0, stream>>>(c12, c11, u_all + lvloff(11),
                                             wr, brs, wh, b_h, wz, bzs, wu, b_u);
    level_kernel<<<1024, 256, 0, stream>>>(u_all + lvloff(11), c10, u_all + lvloff(10),
                                           wr, brs, wh, b_h, wz, bzs, wu, b_u);
    level_kernel<<<512, 256, 0, stream>>>(u_all + lvloff(10), c9, u_all + lvloff(9),
                                          wr, brs, wh, b_h, wz, bzs, wu, b_u);
    fused_mid_regs<<<256, 256, 0, stream>>>(contents, u_all,
                                            wr, brs, wh, b_h, wz, bzs, wu, b_u);
    fused_tail_regs<<<64, 256, 0, stream>>>(contents, u_all,
                                            wr, brs, wh, b_h, wz, bzs, wu, b_u, out);
}